// Round 7
// baseline (692.080 us; speedup 1.0000x reference)
//
#include <hip/hip_runtime.h>

typedef __bf16 bf16;
typedef __attribute__((ext_vector_type(8))) __bf16 bf16x8;
typedef __attribute__((ext_vector_type(4))) __bf16 bf16x4;
typedef __attribute__((ext_vector_type(4))) float f32x4;

#define B_ 16
#define C_ 768
#define T_ 1024
#define S_ 12
#define TP_ (T_ + S_)                // P'' rows per batch (tp = t+s+1 <= 1023+12)
#define NNEG_ 10
#define NCOPY 11
#define NPRED_ROWS 195360            // 16 * sum_{s=0..11}(1023-s)
#define NPRED (NPRED_ROWS * NCOPY)   // 2148960
#define NT_ 12                       // K tiles: 768 / 64
#define TC_ 512                      // t-chunk

__device__ __forceinline__ void gload16(const void* g, void* l) {
    __builtin_amdgcn_global_load_lds(
        (__attribute__((address_space(1))) void*)g,
        (__attribute__((address_space(3))) void*)l, 16, 0, 0);
}

// ---------- W [C][C][S] fp32 -> WtT [S][D=C][C] bf16, coalesced via LDS ----------
__global__ __launch_bounds__(256) void k_wt(const float* __restrict__ W, bf16* __restrict__ WtT) {
    __shared__ float sW[32 * 385];
    const int c0 = blockIdx.x * 32, d0 = blockIdx.y * 32;
    const int tid = threadIdx.x;
#pragma unroll 4
    for (int k = 0; k < 48; ++k) {
        int idx = k * 256 + tid;          // 0..12287
        int c = idx / 384, r = idx % 384; // r = d*12 + s
        sW[c * 385 + r] = W[((size_t)(c0 + c) * C_ + d0) * S_ + r];
    }
    __syncthreads();
#pragma unroll 4
    for (int k = 0; k < 48; ++k) {
        int idx = k * 256 + tid;
        int row = idx >> 5, c = idx & 31; // row = s*32 + d
        int s = row >> 5, d = row & 31;
        WtT[((size_t)s * C_ + d0 + d) * C_ + c0 + c] = (bf16)sW[c * 385 + d * 12 + s];
    }
}

// ---------- x,y [16][C][T] fp32 (batches b0..b0+cb) -> xTc,yTc [cb][T][C] bf16 ----------
__global__ void k_tr2(const float* __restrict__ x, const float* __restrict__ y,
                      bf16* __restrict__ xTc, bf16* __restrict__ yTc, int b0, int cb) {
    __shared__ float tile[32][33];
    int zz = blockIdx.z;
    const float* src = (zz < cb) ? x : y;
    bf16* dst = (zz < cb) ? xTc : yTc;
    int bb = (zz < cb) ? zz : zz - cb;
    int b = b0 + bb;
    int c0 = blockIdx.y * 32, t0 = blockIdx.x * 32;
    int tx = threadIdx.x & 31, ty = threadIdx.x >> 5;  // ty 0..7
#pragma unroll
    for (int i = 0; i < 4; ++i)
        tile[ty + i * 8][tx] = src[((size_t)b * C_ + c0 + ty + i * 8) * T_ + t0 + tx];
    __syncthreads();
#pragma unroll
    for (int i = 0; i < 4; ++i)
        dst[((size_t)bb * T_ + t0 + ty + i * 8) * C_ + c0 + tx] = (bf16)tile[tx][ty + i * 8];
}

// ---------- Phase 1: P''[bb][tp=t+s+1][s][d] = sum_c WtT[s*768+d][c]*xTc[bb][t][c] + bias[d]
// (byte-identical to round 6's verified kernel)
#define SBAR()  __builtin_amdgcn_s_barrier()
#define SCHED() __builtin_amdgcn_sched_barrier(0)
#define LGKM0() asm volatile("s_waitcnt lgkmcnt(0)" ::: "memory")

__global__ __launch_bounds__(512, 2) void k_gemm8(
    const bf16* __restrict__ xTc, const bf16* __restrict__ WtT,
    const float* __restrict__ bias, bf16* __restrict__ P, int tc0)
{
    const int nblk = blockIdx.x;               // n0 = nblk*256
    const int t0   = tc0 + blockIdx.y * 256;   // global t base of this tile
    const int bb   = blockIdx.z;

    const int tid  = threadIdx.x;
    const int wv   = tid >> 6, lane = tid & 63;
    const int mwz  = wv >> 2, nwz = wv & 3;    // 2 x 4 wave grid
    const int quad = lane >> 4, l15 = lane & 15;

    __shared__ __align__(16) bf16 sA[2][256][64];
    __shared__ __align__(16) bf16 sB[2][256][64];

    const int lrow = lane >> 3;
    const int laneOff = lrow * 1536 + (((lane & 7) * 16) ^ (lrow << 4));
    const char* aG = (const char*)(WtT + (size_t)(nblk * 256) * C_) + laneOff;
    const char* bG = (const char*)(xTc + ((size_t)bb * T_ + t0) * C_) + laneOff;
    const int h0 = wv * 16, h1 = wv * 16 + 8;
    const int arw0 = (h0 & 63) + ((h0 >> 6) << 7);
    const int arw1 = (h1 & 63) + ((h1 >> 6) << 7);
    const int brw0 = (h0 & 31) + ((h0 >> 5) << 6);
    const int brw1 = (h1 & 31) + ((h1 >> 5) << 6);

#define STAGE_A(bufn, roff, kt) do { \
    gload16(aG + (size_t)(arw0 + (roff)) * 1536 + (kt) * 128, &sA[bufn][arw0 + (roff)][0]); \
    gload16(aG + (size_t)(arw1 + (roff)) * 1536 + (kt) * 128, &sA[bufn][arw1 + (roff)][0]); \
} while (0)
#define STAGE_B(bufn, roff, kt) do { \
    gload16(bG + (size_t)(brw0 + (roff)) * 1536 + (kt) * 128, &sB[bufn][brw0 + (roff)][0]); \
    gload16(bG + (size_t)(brw1 + (roff)) * 1536 + (kt) * 128, &sB[bufn][brw1 + (roff)][0]); \
} while (0)

    const int csw0 = (quad * 16) ^ ((l15 & 7) << 4);
    const int csw1 = (64 + quad * 16) ^ ((l15 & 7) << 4);
    const char* aRd0 = (const char*)&sA[0][mwz * 128 + l15][0] + csw0;
    const char* aRd1 = (const char*)&sA[0][mwz * 128 + l15][0] + csw1;
    const char* bRd0 = (const char*)&sB[0][nwz * 64 + l15][0] + csw0;
    const char* bRd1 = (const char*)&sB[0][nwz * 64 + l15][0] + csw1;

    f32x4 acc[8][4] = {};

    STAGE_A(0, 0, 0);
    STAGE_A(0, 64, 0);
    STAGE_B(0, 32, 0);
    STAGE_B(0, 0, 0);
    STAGE_A(1, 0, 1);
    STAGE_B(1, 32, 1);
    STAGE_A(1, 64, 1);
    asm volatile("s_waitcnt vmcnt(6)" ::: "memory");
    SCHED(); SBAR(); SCHED();

#pragma unroll 2
    for (int j = 0; j < NT_; ++j) {
        const int cur = j & 1;
        const int coff = cur << 15;
        const char* aC0 = aRd0 + coff; const char* aC1 = aRd1 + coff;
        const char* bC0 = bRd0 + coff; const char* bC1 = bRd1 + coff;

        bf16x8 a03[4][2], a47[4][2], b01[2][2], b23[2][2], b01p[2][2];

        // P0: M0-3 x N0-1 | stage T(j+1).R1 -> buf^1
        if (j + 1 < NT_) STAGE_B(cur ^ 1, 0, j + 1);
#pragma unroll
        for (int i = 0; i < 4; ++i) {
            a03[i][0] = *(const bf16x8*)(aC0 + i * 2048);
            a03[i][1] = *(const bf16x8*)(aC1 + i * 2048);
        }
#pragma unroll
        for (int i = 0; i < 2; ++i) {
            b01[i][0] = *(const bf16x8*)(bC0 + i * 2048);
            b01[i][1] = *(const bf16x8*)(bC1 + i * 2048);
        }
        SCHED(); SBAR(); LGKM0(); SCHED();
        __builtin_amdgcn_s_setprio(1);
#pragma unroll
        for (int i = 0; i < 4; ++i)
#pragma unroll
            for (int n = 0; n < 2; ++n)
#pragma unroll
                for (int kk = 0; kk < 2; ++kk)
                    acc[i][n] = __builtin_amdgcn_mfma_f32_16x16x32_bf16(a03[i][kk], b01[n][kk], acc[i][n], 0, 0, 0);
        __builtin_amdgcn_s_setprio(0);
        SCHED(); SBAR(); SCHED();

        // P1: M0-3 x N2-3 | stage T(j+2).R0
        if (j + 2 < NT_) STAGE_A(cur, 0, j + 2);
#pragma unroll
        for (int i = 0; i < 2; ++i) {
            b23[i][0] = *(const bf16x8*)(bC0 + 4096 + i * 2048);
            b23[i][1] = *(const bf16x8*)(bC1 + 4096 + i * 2048);
        }
        SCHED(); SBAR(); LGKM0(); SCHED();
        __builtin_amdgcn_s_setprio(1);
#pragma unroll
        for (int i = 0; i < 4; ++i)
#pragma unroll
            for (int n = 0; n < 2; ++n)
#pragma unroll
                for (int kk = 0; kk < 2; ++kk)
                    acc[i][2 + n] = __builtin_amdgcn_mfma_f32_16x16x32_bf16(a03[i][kk], b23[n][kk], acc[i][2 + n], 0, 0, 0);
        __builtin_amdgcn_s_setprio(0);
        SCHED(); SBAR(); SCHED();

        // P2: M4-7 x N2-3 | stage T(j+2).R3
        if (j + 2 < NT_) STAGE_B(cur, 32, j + 2);
#pragma unroll
        for (int i = 0; i < 4; ++i) {
            a47[i][0] = *(const bf16x8*)(aC0 + 8192 + i * 2048);
            a47[i][1] = *(const bf16x8*)(aC1 + 8192 + i * 2048);
        }
        SCHED(); SBAR(); LGKM0(); SCHED();
        __builtin_amdgcn_s_setprio(1);
#pragma unroll
        for (int i = 0; i < 4; ++i)
#pragma unroll
            for (int n = 0; n < 2; ++n)
#pragma unroll
                for (int kk = 0; kk < 2; ++kk)
                    acc[4 + i][2 + n] = __builtin_amdgcn_mfma_f32_16x16x32_bf16(a47[i][kk], b23[n][kk], acc[4 + i][2 + n], 0, 0, 0);
        __builtin_amdgcn_s_setprio(0);
        SCHED(); SBAR(); SCHED();

        // P3: M4-7 x N0-1 | stage T(j+2).R2 | gate vmcnt(6)
        if (j + 2 < NT_) STAGE_A(cur, 64, j + 2);
#pragma unroll
        for (int i = 0; i < 2; ++i) {
            b01p[i][0] = *(const bf16x8*)(bC0 + i * 2048);
            b01p[i][1] = *(const bf16x8*)(bC1 + i * 2048);
        }
        if (j < NT_ - 2)       { asm volatile("s_waitcnt vmcnt(6)" ::: "memory"); }
        else if (j == NT_ - 2) { asm volatile("s_waitcnt vmcnt(0)" ::: "memory"); }
        SCHED(); SBAR(); LGKM0(); SCHED();
        __builtin_amdgcn_s_setprio(1);
#pragma unroll
        for (int i = 0; i < 4; ++i)
#pragma unroll
            for (int n = 0; n < 2; ++n)
#pragma unroll
                for (int kk = 0; kk < 2; ++kk)
                    acc[4 + i][n] = __builtin_amdgcn_mfma_f32_16x16x32_bf16(a47[i][kk], b01p[n][kk], acc[4 + i][n], 0, 0, 0);
        __builtin_amdgcn_s_setprio(0);
        SCHED(); SBAR(); SCHED();
    }

    const size_t SC = (size_t)S_ * C_;
    const int sblk = nblk / 3;
    const int dblk = (nblk % 3) * 256;
    bf16* Pb = P + (size_t)bb * TP_ * SC + (size_t)sblk * C_ + dblk;
#pragma unroll
    for (int i = 0; i < 8; ++i) {
        const int nloc = mwz * 128 + i * 16 + quad * 4;
        const f32x4 bv = *(const f32x4*)&bias[dblk + nloc];
#pragma unroll
        for (int n = 0; n < 4; ++n) {
            const int t = t0 + nwz * 64 + n * 16 + l15;
            const int tp = t + sblk + 1;
            bf16x4 v;
#pragma unroll
            for (int r = 0; r < 4; ++r) v[r] = (bf16)(acc[i][n][r] + bv[r]);
            *(bf16x4*)&Pb[(size_t)tp * SC + nloc] = v;
        }
    }
#undef STAGE_A
#undef STAGE_B
}

// ---------- Phase 2: one block (256 thr) per (bb, tp), tp in [tp0, tp0+512).
// XCD-pinned: bb = widx % cb -> with cb multiple of 8, XCD (widx&7) serves only
// batches {x, x+8}: y-pool 2x1.5MB + neg 2x40KB = 3.1 MB -> gathers L2-resident.
// 4-wave K-split: wave w computes kt in [6w, 6w+6) (exact fp32 partial sums),
// partials parked in an sAB alias, wave 0 reduces -> critical path 24->6 MFMAs.
__global__ __launch_bounds__(256, 4) void k_pred(
    const bf16* __restrict__ P, const bf16* __restrict__ yTc,
    const int* __restrict__ neg, float* __restrict__ out, int b0, int tp0, int cb)
{
    const int widx = blockIdx.x;
    const int bb = widx % cb;
    const int tp = tp0 + widx / cb;
    if (tp > T_ - 1) return;               // uniform per block: safe w.r.t. barriers
    const int b = b0 + bb;
    const int tid = threadIdx.x;

    __shared__ __align__(16) char sAB[24 * 1536];   // rows 0-11: P(s); 12-23: targets
    __shared__ int sRid[12];

    if (tid < 12) {
        int ridx;
        if (tid == 0) ridx = bb * T_ + tp;
        else ridx = neg[(size_t)b * (NNEG_ * T_) + (tid - 1) * T_ + tp] - b0 * T_;
        sRid[tid] = ridx;
    }
    __syncthreads();

    const char* Prow = (const char*)(P + ((size_t)bb * TP_ + tp) * (S_ * C_));
#pragma unroll
    for (int i = 0; i < 18; ++i) {
        int idx = i * 256 + tid;        // 0..4607
        int row = idx / 192;            // 0..23
        int off = (idx % 192) * 8;
        unsigned long long v;
        if (row < 12) {
            v = *(const unsigned long long*)(Prow + idx * 8);
        } else {
            v = *(const unsigned long long*)((const char*)(yTc + (size_t)sRid[row - 12] * C_) + off);
        }
        int sb = ((off & ~15) ^ ((row & 7) << 4)) | (off & 8);
        *(unsigned long long*)(&sAB[row * 1536 + sb]) = v;
    }
    __syncthreads();

    const int wv = tid >> 6, lane = tid & 63;
    const int quad = lane >> 4, l15 = lane & 15;

    const int ra = l15 < 12 ? l15 : 11;          // P row (clamped; outputs unused)
    const int rb = 12 + (l15 < 12 ? l15 : 11);   // target row
    const char* pa = sAB + ra * 1536;
    const char* pb = sAB + rb * 1536;
    const int xa = (ra & 7) << 4, xb = (rb & 7) << 4;

    f32x4 acc = {};
#pragma unroll
    for (int k = 0; k < 6; ++k) {
        const int kt = wv * 6 + k;
        const int col = ((kt << 2) + quad) << 4;
        bf16x8 av = *(const bf16x8*)(pa + (col ^ xa));
        bf16x8 bv = *(const bf16x8*)(pb + (col ^ xb));
        acc = __builtin_amdgcn_mfma_f32_16x16x32_bf16(av, bv, acc, 0, 0, 0);
    }

    __syncthreads();                                  // all reads of sAB done
    if (wv > 0) *(f32x4*)&sAB[wv * 1024 + lane * 16] = acc;  // park partials (alias)
    __syncthreads();
    if (wv > 0) return;

#pragma unroll
    for (int w = 1; w < 4; ++w) {
        const f32x4 p = *(const f32x4*)&sAB[w * 1024 + lane * 16];
#pragma unroll
        for (int r = 0; r < 4; ++r) acc[r] += p[r];
    }

#pragma unroll
    for (int r = 0; r < 4; ++r) {
        int s = quad * 4 + r;
        int t = tp - 1 - s;
        if (s < S_ && t >= 0) {
            int rowbase = s * (T_ - 1) - (s * (s - 1)) / 2;
            size_t row = (size_t)(rowbase + t) * B_ + b;
            if (l15 < NCOPY)       out[row * NCOPY + l15] = acc[r];
            else if (l15 == NCOPY) out[NPRED + row] = 0.0f;   // labels
        }
    }
}

extern "C" void kernel_launch(void* const* d_in, const int* in_sizes, int n_in,
                              void* d_out, int out_size, void* d_ws, size_t ws_size,
                              hipStream_t stream) {
    const float* x    = (const float*)d_in[0];
    const float* y    = (const float*)d_in[1];
    const float* W    = (const float*)d_in[2];
    const float* bias = (const float*)d_in[3];
    const int*   neg  = (const int*)d_in[4];
    float* out = (float*)d_out;

    const size_t offW    = (size_t)S_ * C_ * C_ * 2;        // 14,155,776
    const size_t perb_xy = (size_t)T_ * C_ * 2;             // 1,572,864
    const size_t perb_p  = (size_t)TP_ * S_ * C_ * 2;       // 19,095,552
    const size_t perb    = 2 * perb_xy + perb_p;

    int bchunk = (int)((ws_size - offW) / perb);
    if (bchunk < 1) bchunk = 1;
    if (bchunk > B_) bchunk = B_;

    char* ws = (char*)d_ws;
    bf16* WtT = (bf16*)ws;
    bf16* xTc = (bf16*)(ws + offW);
    bf16* yTc = (bf16*)(ws + offW + (size_t)bchunk * perb_xy);
    bf16* P   = (bf16*)(ws + offW + (size_t)bchunk * perb_xy * 2);

    k_wt<<<dim3(C_ / 32, C_ / 32), 256, 0, stream>>>(W, WtT);

    for (int b0 = 0; b0 < B_;) {
        int cb = bchunk < (B_ - b0) ? bchunk : (B_ - b0);
        k_tr2<<<dim3(T_ / 32, C_ / 32, 2 * cb), 256, 0, stream>>>(x, y, xTc, yTc, b0, cb);
        for (int tc = 0; tc < T_; tc += TC_) {
            k_gemm8<<<dim3(36, TC_ / 256, cb), 512, 0, stream>>>(xTc, WtT, bias, P, tc);
            k_pred<<<dim3(cb << 9), 256, 0, stream>>>(P, yTc, neg, out, b0, tc + 1, cb);
        }
        b0 += cb;
    }
}

// Round 8
// 604.206 us; speedup vs baseline: 1.1454x; 1.1454x over previous
//
#include <hip/hip_runtime.h>

typedef __bf16 bf16;
typedef __attribute__((ext_vector_type(8))) __bf16 bf16x8;
typedef __attribute__((ext_vector_type(4))) __bf16 bf16x4;
typedef __attribute__((ext_vector_type(4))) float f32x4;

#define B_ 16
#define C_ 768
#define T_ 1024
#define S_ 12
#define TP_ (T_ + S_)                // P'' rows per batch (tp = t+s+1 <= 1023+12)
#define NNEG_ 10
#define NCOPY 11
#define NPRED_ROWS 195360            // 16 * sum_{s=0..11}(1023-s)
#define NPRED (NPRED_ROWS * NCOPY)   // 2148960
#define NT_ 12                       // K tiles: 768 / 64

__device__ __forceinline__ void gload16(const void* g, void* l) {
    __builtin_amdgcn_global_load_lds(
        (__attribute__((address_space(1))) void*)g,
        (__attribute__((address_space(3))) void*)l, 16, 0, 0);
}

// ---------- W [C][C][S] fp32 -> WtT [S][D=C][C] bf16, coalesced via LDS ----------
__global__ __launch_bounds__(256) void k_wt(const float* __restrict__ W, bf16* __restrict__ WtT) {
    __shared__ float sW[32 * 385];
    const int c0 = blockIdx.x * 32, d0 = blockIdx.y * 32;
    const int tid = threadIdx.x;
#pragma unroll 4
    for (int k = 0; k < 48; ++k) {
        int idx = k * 256 + tid;          // 0..12287
        int c = idx / 384, r = idx % 384; // r = d*12 + s
        sW[c * 385 + r] = W[((size_t)(c0 + c) * C_ + d0) * S_ + r];
    }
    __syncthreads();
#pragma unroll 4
    for (int k = 0; k < 48; ++k) {
        int idx = k * 256 + tid;
        int row = idx >> 5, c = idx & 31; // row = s*32 + d
        int s = row >> 5, d = row & 31;
        WtT[((size_t)s * C_ + d0 + d) * C_ + c0 + c] = (bf16)sW[c * 385 + d * 12 + s];
    }
}

// ---------- x,y [16][C][T] fp32 (batches b0..b0+cb) -> xTc,yTc [cb][T][C] bf16 ----------
__global__ void k_tr2(const float* __restrict__ x, const float* __restrict__ y,
                      bf16* __restrict__ xTc, bf16* __restrict__ yTc, int b0, int cb) {
    __shared__ float tile[32][33];
    int zz = blockIdx.z;
    const float* src = (zz < cb) ? x : y;
    bf16* dst = (zz < cb) ? xTc : yTc;
    int bb = (zz < cb) ? zz : zz - cb;
    int b = b0 + bb;
    int c0 = blockIdx.y * 32, t0 = blockIdx.x * 32;
    int tx = threadIdx.x & 31, ty = threadIdx.x >> 5;  // ty 0..7
#pragma unroll
    for (int i = 0; i < 4; ++i)
        tile[ty + i * 8][tx] = src[((size_t)b * C_ + c0 + ty + i * 8) * T_ + t0 + tx];
    __syncthreads();
#pragma unroll
    for (int i = 0; i < 4; ++i)
        dst[((size_t)bb * T_ + t0 + ty + i * 8) * C_ + c0 + tx] = (bf16)tile[tx][ty + i * 8];
}

// ---------- Phase 1: P''[bb][tp=t+s+1][s][d] = sum_c WtT[s*768+d][c]*xTc[bb][t][c] + bias[d]
// 256x256 tile, BK=64, 8 waves (2M x 4N).
// TWO phases per K-tile (was 4), THREE barriers per K-tile (was 8):
//   P0: M0-3 x all-N (reads a03 8 + B 8), stages B(j+1)+A.R2(j+1) -> buf^1, gate vmcnt(8)
//   P1: M4-7 x all-N (reads a47 8; B reused from registers), stages A.R0(j+2) -> buf cur
// Region safety: R0 read only at P0 (barrier before P1's stage); R2 staged one
// phase after its last read (prev tile P1); B 2-buffer alternation as before.
// Uniform vmcnt(8) gate (clamped dummy stages keep the tail uniform); ledger:
// in-flight at gate = A.R0(j+1)[2] + this-P0 batch[6] = 8.
#define SBAR()  __builtin_amdgcn_s_barrier()
#define SCHED() __builtin_amdgcn_sched_barrier(0)
#define LGKM0() asm volatile("s_waitcnt lgkmcnt(0)" ::: "memory")

__global__ __launch_bounds__(512, 2) void k_gemm8(
    const bf16* __restrict__ xTc, const bf16* __restrict__ WtT,
    const float* __restrict__ bias, bf16* __restrict__ P)
{
    const int nblk = blockIdx.x;               // n0 = nblk*256
    const int t0   = blockIdx.y * 256;         // t base of this tile
    const int bb   = blockIdx.z;

    const int tid  = threadIdx.x;
    const int wv   = tid >> 6, lane = tid & 63;
    const int mwz  = wv >> 2, nwz = wv & 3;    // 2 x 4 wave grid
    const int quad = lane >> 4, l15 = lane & 15;

    __shared__ __align__(16) bf16 sA[2][256][64];
    __shared__ __align__(16) bf16 sB[2][256][64];

    // ---- staging (write) addressing ----
    const int lrow = lane >> 3;
    const int laneOff = lrow * 1536 + (((lane & 7) * 16) ^ (lrow << 4));
    const char* aG = (const char*)(WtT + (size_t)(nblk * 256) * C_) + laneOff;
    const char* bG = (const char*)(xTc + ((size_t)bb * T_ + t0) * C_) + laneOff;
    const int h0 = wv * 16, h1 = wv * 16 + 8;
    const int arw0 = (h0 & 63) + ((h0 >> 6) << 7);
    const int arw1 = (h1 & 63) + ((h1 >> 6) << 7);
    const int brw0 = (h0 & 31) + ((h0 >> 5) << 6);
    const int brw1 = (h1 & 31) + ((h1 >> 5) << 6);

#define STAGE_A(bufn, roff, kt) do { \
    gload16(aG + (size_t)(arw0 + (roff)) * 1536 + (kt) * 128, &sA[bufn][arw0 + (roff)][0]); \
    gload16(aG + (size_t)(arw1 + (roff)) * 1536 + (kt) * 128, &sA[bufn][arw1 + (roff)][0]); \
} while (0)
#define STAGE_B(bufn, roff, kt) do { \
    gload16(bG + (size_t)(brw0 + (roff)) * 1536 + (kt) * 128, &sB[bufn][brw0 + (roff)][0]); \
    gload16(bG + (size_t)(brw1 + (roff)) * 1536 + (kt) * 128, &sB[bufn][brw1 + (roff)][0]); \
} while (0)

    // ---- fragment (read) addressing ----
    const int csw0 = (quad * 16) ^ ((l15 & 7) << 4);
    const int csw1 = (64 + quad * 16) ^ ((l15 & 7) << 4);
    const char* aRd0 = (const char*)&sA[0][mwz * 128 + l15][0] + csw0;
    const char* aRd1 = (const char*)&sA[0][mwz * 128 + l15][0] + csw1;
    const char* bRd0 = (const char*)&sB[0][nwz * 64 + l15][0] + csw0;
    const char* bRd1 = (const char*)&sB[0][nwz * 64 + l15][0] + csw1;

    f32x4 acc[8][4] = {};

    // ---- prologue: A.R0(0), B(0), A.R2(0), A.R0(1) = 10 loads ----
    STAGE_A(0, 0, 0);
    STAGE_B(0, 0, 0);
    STAGE_B(0, 32, 0);
    STAGE_A(0, 64, 0);
    STAGE_A(1, 0, 1);

#pragma unroll 2
    for (int j = 0; j < NT_; ++j) {
        const int cur = j & 1;
        const int coff = cur << 15;
        const char* aC0 = aRd0 + coff; const char* aC1 = aRd1 + coff;
        const char* bC0 = bRd0 + coff; const char* bC1 = bRd1 + coff;
        const int kt1 = (j + 1 < NT_) ? j + 1 : 0;   // clamped: dummy stages keep
        const int kt2 = (j + 2 < NT_) ? j + 2 : 0;   // the vmcnt ledger uniform

        bf16x8 a03[4][2], a47[4][2], bfr[4][2];

        // -------- P0: M0-3 x N0-3 | stage B(j+1)+A.R2(j+1) -> buf^1 --------
        STAGE_B(cur ^ 1, 0, kt1);
        STAGE_B(cur ^ 1, 32, kt1);
        STAGE_A(cur ^ 1, 64, kt1);
        asm volatile("s_waitcnt vmcnt(8)" ::: "memory");   // tile j landed (own wave)
        SCHED(); SBAR(); SCHED();                           // all waves' tile j landed
#pragma unroll
        for (int i = 0; i < 4; ++i) {
            a03[i][0] = *(const bf16x8*)(aC0 + i * 2048);
            a03[i][1] = *(const bf16x8*)(aC1 + i * 2048);
        }
#pragma unroll
        for (int n = 0; n < 4; ++n) {
            bfr[n][0] = *(const bf16x8*)(bC0 + n * 2048);
            bfr[n][1] = *(const bf16x8*)(bC1 + n * 2048);
        }
        LGKM0(); SCHED();
        __builtin_amdgcn_s_setprio(1);
#pragma unroll
        for (int i = 0; i < 4; ++i)
#pragma unroll
            for (int n = 0; n < 4; ++n)
#pragma unroll
                for (int kk = 0; kk < 2; ++kk)
                    acc[i][n] = __builtin_amdgcn_mfma_f32_16x16x32_bf16(a03[i][kk], bfr[n][kk], acc[i][n], 0, 0, 0);
        __builtin_amdgcn_s_setprio(0);
        SCHED(); SBAR(); SCHED();   // R0 reads complete before P1's stage

        // -------- P1: M4-7 x N0-3 | stage A.R0(j+2) -> buf cur --------
        STAGE_A(cur, 0, kt2);
#pragma unroll
        for (int i = 0; i < 4; ++i) {
            a47[i][0] = *(const bf16x8*)(aC0 + 8192 + i * 2048);
            a47[i][1] = *(const bf16x8*)(aC1 + 8192 + i * 2048);
        }
        LGKM0(); SCHED();
        __builtin_amdgcn_s_setprio(1);
#pragma unroll
        for (int i = 0; i < 4; ++i)
#pragma unroll
            for (int n = 0; n < 4; ++n)
#pragma unroll
                for (int kk = 0; kk < 2; ++kk)
                    acc[4 + i][n] = __builtin_amdgcn_mfma_f32_16x16x32_bf16(a47[i][kk], bfr[n][kk], acc[4 + i][n], 0, 0, 0);
        __builtin_amdgcn_s_setprio(0);
        SCHED(); SBAR(); SCHED();
    }
    asm volatile("s_waitcnt vmcnt(0)" ::: "memory");   // drain clamped dummy stages

    // ---- epilogue: anti-diagonal store (cached). s is block-constant. ----
    const size_t SC = (size_t)S_ * C_;
    const int sblk = nblk / 3;
    const int dblk = (nblk % 3) * 256;
    bf16* Pb = P + (size_t)bb * TP_ * SC + (size_t)sblk * C_ + dblk;
#pragma unroll
    for (int i = 0; i < 8; ++i) {
        const int nloc = mwz * 128 + i * 16 + quad * 4;
        const f32x4 bv = *(const f32x4*)&bias[dblk + nloc];
#pragma unroll
        for (int n = 0; n < 4; ++n) {
            const int t = t0 + nwz * 64 + n * 16 + l15;
            const int tp = t + sblk + 1;
            bf16x4 v;
#pragma unroll
            for (int r = 0; r < 4; ++r) v[r] = (bf16)(acc[i][n][r] + bv[r]);
            *(bf16x4*)&Pb[(size_t)tp * SC + nloc] = v;
        }
    }
#undef STAGE_A
#undef STAGE_B
}

// ---------- Phase 2: one block (256 thr) per (bb, tp). Full-T launch.
// XCD-pinned: bb = widx % cb. 4-wave K-split, wave 0 reduces + writes.
__global__ __launch_bounds__(256, 4) void k_pred(
    const bf16* __restrict__ P, const bf16* __restrict__ yTc,
    const int* __restrict__ neg, float* __restrict__ out, int b0, int tp0, int cb)
{
    const int widx = blockIdx.x;
    const int bb = widx % cb;
    const int tp = tp0 + widx / cb;
    if (tp > T_ - 1) return;               // uniform per block
    const int b = b0 + bb;
    const int tid = threadIdx.x;

    __shared__ __align__(16) char sAB[24 * 1536];   // rows 0-11: P(s); 12-23: targets
    __shared__ int sRid[12];

    if (tid < 12) {
        int ridx;
        if (tid == 0) ridx = bb * T_ + tp;
        else ridx = neg[(size_t)b * (NNEG_ * T_) + (tid - 1) * T_ + tp] - b0 * T_;
        sRid[tid] = ridx;
    }
    __syncthreads();

    const char* Prow = (const char*)(P + ((size_t)bb * TP_ + tp) * (S_ * C_));
#pragma unroll
    for (int i = 0; i < 18; ++i) {
        int idx = i * 256 + tid;        // 0..4607
        int row = idx / 192;            // 0..23
        int off = (idx % 192) * 8;
        unsigned long long v;
        if (row < 12) {
            v = *(const unsigned long long*)(Prow + idx * 8);
        } else {
            v = *(const unsigned long long*)((const char*)(yTc + (size_t)sRid[row - 12] * C_) + off);
        }
        int sb = ((off & ~15) ^ ((row & 7) << 4)) | (off & 8);
        *(unsigned long long*)(&sAB[row * 1536 + sb]) = v;
    }
    __syncthreads();

    const int wv = tid >> 6, lane = tid & 63;
    const int quad = lane >> 4, l15 = lane & 15;

    const int ra = l15 < 12 ? l15 : 11;          // P row (clamped; outputs unused)
    const int rb = 12 + (l15 < 12 ? l15 : 11);   // target row
    const char* pa = sAB + ra * 1536;
    const char* pb = sAB + rb * 1536;
    const int xa = (ra & 7) << 4, xb = (rb & 7) << 4;

    f32x4 acc = {};
#pragma unroll
    for (int k = 0; k < 6; ++k) {
        const int kt = wv * 6 + k;
        const int col = ((kt << 2) + quad) << 4;
        bf16x8 av = *(const bf16x8*)(pa + (col ^ xa));
        bf16x8 bv = *(const bf16x8*)(pb + (col ^ xb));
        acc = __builtin_amdgcn_mfma_f32_16x16x32_bf16(av, bv, acc, 0, 0, 0);
    }

    __syncthreads();                                  // all reads of sAB done
    if (wv > 0) *(f32x4*)&sAB[wv * 1024 + lane * 16] = acc;  // park partials (alias)
    __syncthreads();
    if (wv > 0) return;

#pragma unroll
    for (int w = 1; w < 4; ++w) {
        const f32x4 p = *(const f32x4*)&sAB[w * 1024 + lane * 16];
#pragma unroll
        for (int r = 0; r < 4; ++r) acc[r] += p[r];
    }

#pragma unroll
    for (int r = 0; r < 4; ++r) {
        int s = quad * 4 + r;
        int t = tp - 1 - s;
        if (s < S_ && t >= 0) {
            int rowbase = s * (T_ - 1) - (s * (s - 1)) / 2;
            size_t row = (size_t)(rowbase + t) * B_ + b;
            if (l15 < NCOPY)       out[row * NCOPY + l15] = acc[r];
            else if (l15 == NCOPY) out[NPRED + row] = 0.0f;   // labels
        }
    }
}

extern "C" void kernel_launch(void* const* d_in, const int* in_sizes, int n_in,
                              void* d_out, int out_size, void* d_ws, size_t ws_size,
                              hipStream_t stream) {
    const float* x    = (const float*)d_in[0];
    const float* y    = (const float*)d_in[1];
    const float* W    = (const float*)d_in[2];
    const float* bias = (const float*)d_in[3];
    const int*   neg  = (const int*)d_in[4];
    float* out = (float*)d_out;

    const size_t offW    = (size_t)S_ * C_ * C_ * 2;        // 14,155,776
    const size_t perb_xy = (size_t)T_ * C_ * 2;             // 1,572,864
    const size_t perb_p  = (size_t)TP_ * S_ * C_ * 2;       // 19,095,552
    const size_t perb    = 2 * perb_xy + perb_p;

    int bchunk = (int)((ws_size - offW) / perb);
    if (bchunk < 1) bchunk = 1;
    if (bchunk > B_) bchunk = B_;

    char* ws = (char*)d_ws;
    bf16* WtT = (bf16*)ws;
    bf16* xTc = (bf16*)(ws + offW);
    bf16* yTc = (bf16*)(ws + offW + (size_t)bchunk * perb_xy);
    bf16* P   = (bf16*)(ws + offW + (size_t)bchunk * perb_xy * 2);

    k_wt<<<dim3(C_ / 32, C_ / 32), 256, 0, stream>>>(W, WtT);

    for (int b0 = 0; b0 < B_;) {
        int cb = bchunk < (B_ - b0) ? bchunk : (B_ - b0);
        k_tr2<<<dim3(T_ / 32, C_ / 32, 2 * cb), 256, 0, stream>>>(x, y, xTc, yTc, b0, cb);
        k_gemm8<<<dim3(36, 4, cb), 512, 0, stream>>>(xTc, WtT, bias, P);
        k_pred<<<dim3(cb * 1023), 256, 0, stream>>>(P, yTc, neg, out, b0, 1, cb);
        b0 += cb;
    }
}